// Round 5
// baseline (188.088 us; speedup 1.0000x reference)
//
#include <hip/hip_runtime.h>

// RelationalGraphConvLayer: out[b,m,u] = relu(sum_e (adj[b,e]@feat[b]) @ ker[b,e])
// B=256, E=5, N=128, ATOM=64, UNITS=128, fp32 in/out, bf16 MFMA compute.
//
// R5 = R4 with the compile fix (bit-arithmetic RNE bf16 pack instead of
// __builtin_bit_cast of __hip_bfloat162, which is not trivially copyable).
//
// Design: grid=1024 (sample x row-quarter, 32 rows/block), block=256 = 4 waves
// = (2 m-tiles) x (2 u-halves); mm1 duplicated across the u-pair (MFMA idle).
// Staging rule: every LDS transpose STORE instruction writes ONE row with lanes
// at consecutive columns (conflict-free); source global loads are 16B/lane with
// L1-reused stride (no 16x L2 gather amplification like R3). Reads keep R3's
// XOR chunk swizzle. kerT single-buffered -> LDS 40KB -> 4 blocks/CU, grid
// fully resident, zero tail.

typedef __attribute__((ext_vector_type(8))) short s8v;  // 8 x bf16 MFMA A/B frag
typedef __attribute__((ext_vector_type(4))) float f4v;

__device__ __forceinline__ unsigned bfr(float f) {  // fp32 -> bf16 (RNE), in low 16
    unsigned u = __builtin_bit_cast(unsigned, f);
    u += 0x7FFFu + ((u >> 16) & 1u);
    return u >> 16;
}
__device__ __forceinline__ unsigned pk2(float a, float b) {  // [b|a] packed bf16x2
    return bfr(a) | (bfr(b) << 16);
}
__device__ __forceinline__ s8v mk_frag(f4v lo, f4v hi) {
    union { unsigned u[4]; s8v s; } r;
    r.u[0] = pk2(lo[0], lo[1]); r.u[1] = pk2(lo[2], lo[3]);
    r.u[2] = pk2(hi[0], hi[1]); r.u[3] = pk2(hi[2], hi[3]);
    return r.s;
}
// Swizzled element addresses: 16B chunk c of row r stored at c^(r&7).
__device__ __forceinline__ int adrF(int d, int n) {  // featT[d][n], 128-short rows
    return d * 128 + (((n >> 3) ^ (d & 7)) << 3) + (n & 7);
}
__device__ __forceinline__ int adrK(int u, int d) {  // kerT/YB [row][d], 64-short rows
    return u * 64 + (((d >> 3) ^ (u & 7)) << 3) + (d & 7);
}

__global__ __launch_bounds__(256, 4)
void rgc_kernel(const float* __restrict__ adj,
                const float* __restrict__ feat,
                const float* __restrict__ ker,
                float* __restrict__ out)
{
    __shared__ __align__(16) short featT[64 * 128];   // 16 KB  [d][n]
    __shared__ __align__(16) short kerT[128 * 64];    // 16 KB  [u][d] (single buf)
    __shared__ __align__(16) short YB[4][16 * 64];    //  8 KB  per-wave [m][d]

    const int bs   = blockIdx.x & 255;   // sample
    const int Q    = blockIdx.x >> 8;    // row quarter
    const int tid  = threadIdx.x;
    const int w    = tid >> 6;           // wave 0..3
    const int mt   = w >> 1;             // m-tile (16 rows)
    const int uh   = w & 1;              // u half (64 units)
    const int lane = tid & 63;
    const int c16  = lane & 15;
    const int quad = lane >> 4;

    const float* adjB  = adj  + (size_t)bs * (5 * 128 * 128);
    const float* featB = feat + (size_t)bs * (128 * 64);
    const float* kerB  = ker  + (size_t)bs * (5 * 64 * 128);
    float*       outB  = out  + (size_t)bs * (128 * 128);

    // ---- stage featT[d][n]=feat[n][d]: thread owns row n=tid&127, d-half ----
    // Loads: 8 x f4v along d (16B/lane; 8KB wave footprint, L1-reused).
    // Stores: per instr d is wave-uniform, lanes n consecutive -> conflict-free.
    {
        const int sn = tid & 127, sdh = tid >> 7;
        const float* fp = featB + sn * 64 + sdh * 32;
        f4v v[8];
        #pragma unroll
        for (int i = 0; i < 8; ++i) v[i] = *(const f4v*)(fp + 4 * i);
        #pragma unroll
        for (int i = 0; i < 8; ++i)
            #pragma unroll
            for (int j = 0; j < 4; ++j) {
                const int d = 32 * sdh + 4 * i + j;
                featT[adrF(d, sn)] = (short)bfr(v[i][j]);
            }
    }
    // ---- stage kerT[u][d]=ker[0][d][u]: thread owns column d=lane, u-range 32w ----
    {
        const float* kp = kerB + lane * 128 + 32 * w;
        f4v v[8];
        #pragma unroll
        for (int i = 0; i < 8; ++i) v[i] = *(const f4v*)(kp + 4 * i);
        #pragma unroll
        for (int i = 0; i < 8; ++i)
            #pragma unroll
            for (int j = 0; j < 4; ++j) {
                const int u = 32 * w + 4 * i + j;   // wave-uniform per instr
                kerT[adrK(u, lane)] = (short)bfr(v[i][j]);
            }
    }
    __syncthreads();

    const int rowS = 32 * Q + 16 * mt;
    const float* ap0 = adjB + (rowS + c16) * 128 + 8 * quad;
    short* YBw = YB[w];

    f4v oacc[4] = {};  // 16 rows x 64 units (4 u16 tiles)

    for (int e = 0; e < 5; ++e) {
        // ---- adjacency A-frags: this wave's 16 rows straight from global ----
        const float* ap = ap0 + e * 16384;
        f4v a0[4], a1[4];
        #pragma unroll
        for (int k16 = 0; k16 < 4; ++k16) {
            a0[k16] = *(const f4v*)(ap + 32 * k16);
            a1[k16] = *(const f4v*)(ap + 32 * k16 + 4);
        }
        // ---- issue next-e ker loads (in flight across mm1 + YB + mm2) ----
        f4v kv[8];
        if (e < 4) {
            const float* kp = kerB + (e + 1) * 8192 + lane * 128 + 32 * w;
            #pragma unroll
            for (int i = 0; i < 8; ++i) kv[i] = *(const f4v*)(kp + 4 * i);
        }

        // ---- matmul1: Y[16 rows][64 d] = adj_e @ feat  (K=128) ----
        f4v yacc[4] = {};
        #pragma unroll
        for (int k16 = 0; k16 < 4; ++k16) {
            s8v af = mk_frag(a0[k16], a1[k16]);
            #pragma unroll
            for (int d16 = 0; d16 < 4; ++d16) {
                const int d = 16 * d16 + c16;
                s8v bf = *(const s8v*)&featT[d * 128 + (((4 * k16 + quad) ^ (d & 7)) << 3)];
                yacc[d16] = __builtin_amdgcn_mfma_f32_16x16x32_bf16(af, bf, yacc[d16], 0, 0, 0);
            }
        }

        // ---- Y: C/D layout -> A-operand layout via wave-private swizzled LDS ----
        #pragma unroll
        for (int d16 = 0; d16 < 4; ++d16)
            #pragma unroll
            for (int r = 0; r < 4; ++r) {
                const int m = 4 * quad + r;
                YBw[adrK(m, 16 * d16 + c16)] = (short)bfr(yacc[d16][r]);
            }
        s8v y0 = *(const s8v*)&YBw[c16 * 64 + ((quad ^ (c16 & 7)) << 3)];
        s8v y1 = *(const s8v*)&YBw[c16 * 64 + (((4 + quad) ^ (c16 & 7)) << 3)];

        // ---- matmul2: oacc += Y @ ker_e for this wave's u-half (K=64) ----
        #pragma unroll
        for (int u16 = 0; u16 < 4; ++u16) {
            const int uc = 64 * uh + 16 * u16 + c16;
            s8v b0 = *(const s8v*)&kerT[uc * 64 + ((quad ^ (uc & 7)) << 3)];
            s8v b1 = *(const s8v*)&kerT[uc * 64 + (((4 + quad) ^ (uc & 7)) << 3)];
            oacc[u16] = __builtin_amdgcn_mfma_f32_16x16x32_bf16(y0, b0, oacc[u16], 0, 0, 0);
            oacc[u16] = __builtin_amdgcn_mfma_f32_16x16x32_bf16(y1, b1, oacc[u16], 0, 0, 0);
        }

        // ---- rotate kerT (single buffer): drain readers, restage, release ----
        if (e < 4) {
            __syncthreads();
            #pragma unroll
            for (int i = 0; i < 8; ++i)
                #pragma unroll
                for (int j = 0; j < 4; ++j) {
                    const int u = 32 * w + 4 * i + j;
                    kerT[adrK(u, lane)] = (short)bfr(kv[i][j]);
                }
            __syncthreads();
        }
    }

    // ---- epilogue: relu + store ----
    #pragma unroll
    for (int u16 = 0; u16 < 4; ++u16)
        #pragma unroll
        for (int r = 0; r < 4; ++r)
            outB[(rowS + 4 * quad + r) * 128 + 64 * uh + 16 * u16 + c16] =
                fmaxf(oacc[u16][r], 0.f);
}

extern "C" void kernel_launch(void* const* d_in, const int* in_sizes, int n_in,
                              void* d_out, int out_size, void* d_ws, size_t ws_size,
                              hipStream_t stream)
{
    const float* adj  = (const float*)d_in[0];
    const float* feat = (const float*)d_in[1];
    const float* ker  = (const float*)d_in[2];
    rgc_kernel<<<1024, 256, 0, stream>>>(adj, feat, ker, (float*)d_out);
}

// Round 6
// 180.315 us; speedup vs baseline: 1.0431x; 1.0431x over previous
//
#include <hip/hip_runtime.h>

// RelationalGraphConvLayer: out[b,m,u] = relu(sum_e (adj[b,e]@feat[b]) @ ker[b,e])
// B=256, E=5, N=128, ATOM=64, UNITS=128, fp32 in/out, bf16 MFMA compute.
//
// R6: two barrier-free streaming kernels through a d_ws intermediate.
//  K1: Y[b,e] = adj[b,e] @ feat[b]  -> d_ws, PRE-PACKED as MFMA A-frags
//      (lane-contiguous 16B/lane stores). grid (5,256), block 512 (8 m-tile
//      waves). One barrier (featT stage) then free-running adj stream.
//      1280 blocks -> 4 resident/CU = 32 waves/CU.
//  K2: out[b] = relu(sum_e Y[b,e] @ ker[b,e]). grid 512 (b x u-half),
//      block 512 (8 m-tile waves). kerT (u-half, all 5 e, 40KB swizzled)
//      staged once behind in-flight Y loads; one barrier; 40 MFMA, no
//      further sync. u-half split keeps ker read exactly once (256B-aligned).
// Rationale: every fused design (R1-R5) was barrier-coupled at 2 syncs/e with
// MFMA<5% to hide the drain; dur tracked traffic+coupling, not occupancy.

typedef __attribute__((ext_vector_type(8))) short s8v;  // 8 x bf16 frag
typedef __attribute__((ext_vector_type(4))) float f4v;

__device__ __forceinline__ unsigned bfr(float f) {  // fp32->bf16 RNE (low 16)
    unsigned u = __builtin_bit_cast(unsigned, f);
    u += 0x7FFFu + ((u >> 16) & 1u);
    return u >> 16;
}
__device__ __forceinline__ unsigned pk2(float a, float b) {
    return bfr(a) | (bfr(b) << 16);
}
__device__ __forceinline__ s8v mk_frag(f4v lo, f4v hi) {
    union { unsigned u[4]; s8v s; } r;
    r.u[0] = pk2(lo[0], lo[1]); r.u[1] = pk2(lo[2], lo[3]);
    r.u[2] = pk2(hi[0], hi[1]); r.u[3] = pk2(hi[2], hi[3]);
    return r.s;
}
// XOR chunk swizzle: 16B chunk c of row r lives at c^(r&7).
__device__ __forceinline__ int adrF(int d, int n) {   // rows of 128 shorts
    return d * 128 + (((n >> 3) ^ (d & 7)) << 3) + (n & 7);
}
__device__ __forceinline__ int adrK(int r, int c) {   // rows of 64 shorts
    return r * 64 + (((c >> 3) ^ (r & 7)) << 3) + (c & 7);
}

// ---------------- Kernel 1: Y = adj @ feat, packed A-frags ----------------
__global__ __launch_bounds__(512, 2)
void rgc_mm1(const float* __restrict__ adj, const float* __restrict__ feat,
             short* __restrict__ yws)
{
    __shared__ __align__(16) short featT[64 * 128];  // 16 KB [d][n]
    __shared__ __align__(16) short YB[8][16 * 64];   // 16 KB wave-private remap

    const int e = blockIdx.x, b = blockIdx.y;
    const int tid = threadIdx.x;
    const int w = tid >> 6, lane = tid & 63;
    const int c16 = lane & 15, quad = lane >> 4;

    const float* adjE  = adj  + ((size_t)b * 5 + e) * 16384;
    const float* featB = feat + (size_t)b * 8192;

    // stage featT[d][n]=feat[n][d]: per-instr d wave-uniform, lanes n
    // consecutive -> conflict-free; per-lane 64B contiguous global reads.
    {
        const int sn = tid & 127;      // n (lanes consecutive in wave)
        const int dq = tid >> 7;       // d-quarter (wave-uniform)
        const float* fp = featB + sn * 64 + dq * 16;
        f4v v[4];
        #pragma unroll
        for (int i = 0; i < 4; ++i) v[i] = *(const f4v*)(fp + 4 * i);
        #pragma unroll
        for (int i = 0; i < 4; ++i)
            #pragma unroll
            for (int j = 0; j < 4; ++j)
                featT[adrF(16 * dq + 4 * i + j, sn)] = (short)bfr(v[i][j]);
    }
    __syncthreads();  // only barrier

    // wave w: rows 16w..16w+16 of adj_e
    const float* ap = adjE + (16 * w + c16) * 128 + 8 * quad;
    f4v a0[4], a1[4];
    #pragma unroll
    for (int k16 = 0; k16 < 4; ++k16) {
        a0[k16] = *(const f4v*)(ap + 32 * k16);
        a1[k16] = *(const f4v*)(ap + 32 * k16 + 4);
    }
    f4v yacc[4] = {};
    #pragma unroll
    for (int k16 = 0; k16 < 4; ++k16) {
        s8v af = mk_frag(a0[k16], a1[k16]);
        #pragma unroll
        for (int d16 = 0; d16 < 4; ++d16) {
            const int d = 16 * d16 + c16;
            s8v bf = *(const s8v*)&featT[d * 128 + (((4 * k16 + quad) ^ (d & 7)) << 3)];
            yacc[d16] = __builtin_amdgcn_mfma_f32_16x16x32_bf16(af, bf, yacc[d16], 0, 0, 0);
        }
    }
    // C/D layout -> A-operand layout via wave-private swizzled LDS
    short* YBw = YB[w];
    #pragma unroll
    for (int d16 = 0; d16 < 4; ++d16)
        #pragma unroll
        for (int r = 0; r < 4; ++r) {
            const int m = 4 * quad + r;
            YBw[adrK(m, 16 * d16 + c16)] = (short)bfr(yacc[d16][r]);
        }
    s8v y0 = *(const s8v*)&YBw[c16 * 64 + ((quad ^ (c16 & 7)) << 3)];
    s8v y1 = *(const s8v*)&YBw[c16 * 64 + (((4 + quad) ^ (c16 & 7)) << 3)];
    // packed A-frag store: lane-contiguous 16B -> 1KB coalesced per instr
    short* yp = yws + (((size_t)b * 5 + e) * 8 + w) * 1024;
    *(s8v*)(yp + lane * 8)       = y0;   // K-tile 0 (d 0..31)
    *(s8v*)(yp + 512 + lane * 8) = y1;   // K-tile 1 (d 32..63)
}

// ---------------- Kernel 2: out = relu(sum_e Y @ ker) ----------------
__global__ __launch_bounds__(512, 2)
void rgc_mm2(const short* __restrict__ yws, const float* __restrict__ ker,
             float* __restrict__ out)
{
    __shared__ __align__(16) short kerT[5 * 64 * 64];  // 40 KB [e][u'][d]

    const int b = blockIdx.x & 255, uh = blockIdx.x >> 8;
    const int tid = threadIdx.x;
    const int w = tid >> 6, lane = tid & 63;    // wave w = m-tile, rows 16w..
    const int c16 = lane & 15, quad = lane >> 4;

    const float* kerB  = ker + (size_t)b * 40960 + 64 * uh;
    const short* ybase = yws + (size_t)b * 5 * 8192;

    // Y A-frag loads FIRST (in flight across kerT staging + barrier)
    s8v y0[5], y1[5];
    #pragma unroll
    for (int e = 0; e < 5; ++e) {
        const short* yp = ybase + (e * 8 + w) * 1024 + lane * 8;
        y0[e] = *(const s8v*)yp;
        y1[e] = *(const s8v*)(yp + 512);
    }
    // stage kerT[e][u'][d]=ker[e][d][64uh+u']: per-instr u' uniform, lanes
    // d consecutive -> conflict-free; 32B/lane contiguous global reads,
    // 8 waves cover the full 256B half-row (128B-line aligned).
    #pragma unroll
    for (int e = 0; e < 5; ++e) {
        const float* kp = kerB + e * 8192 + lane * 128 + 8 * w;
        f4v v0 = *(const f4v*)kp, v1 = *(const f4v*)(kp + 4);
        #pragma unroll
        for (int j = 0; j < 4; ++j)
            kerT[e * 4096 + adrK(8 * w + j, lane)] = (short)bfr(v0[j]);
        #pragma unroll
        for (int j = 0; j < 4; ++j)
            kerT[e * 4096 + adrK(8 * w + 4 + j, lane)] = (short)bfr(v1[j]);
    }
    __syncthreads();  // only barrier

    f4v oacc[4] = {};  // 16 rows x 64 units
    #pragma unroll
    for (int e = 0; e < 5; ++e)
        #pragma unroll
        for (int u16 = 0; u16 < 4; ++u16) {
            const int uc = 16 * u16 + c16;  // local u row in this half
            s8v b0 = *(const s8v*)&kerT[e * 4096 + uc * 64 + ((quad ^ (uc & 7)) << 3)];
            s8v b1 = *(const s8v*)&kerT[e * 4096 + uc * 64 + (((4 + quad) ^ (uc & 7)) << 3)];
            oacc[u16] = __builtin_amdgcn_mfma_f32_16x16x32_bf16(y0[e], b0, oacc[u16], 0, 0, 0);
            oacc[u16] = __builtin_amdgcn_mfma_f32_16x16x32_bf16(y1[e], b1, oacc[u16], 0, 0, 0);
        }

    float* outB = out + (size_t)b * 16384;
    #pragma unroll
    for (int u16 = 0; u16 < 4; ++u16)
        #pragma unroll
        for (int r = 0; r < 4; ++r)
            outB[(16 * w + 4 * quad + r) * 128 + 64 * uh + 16 * u16 + c16] =
                fmaxf(oacc[u16][r], 0.f);
}

extern "C" void kernel_launch(void* const* d_in, const int* in_sizes, int n_in,
                              void* d_out, int out_size, void* d_ws, size_t ws_size,
                              hipStream_t stream)
{
    const float* adj  = (const float*)d_in[0];
    const float* feat = (const float*)d_in[1];
    const float* ker  = (const float*)d_in[2];
    short* yws = (short*)d_ws;  // needs 256*5*8192*2 B = 20.97 MB
    rgc_mm1<<<dim3(5, 256), 512, 0, stream>>>(adj, feat, yws);
    rgc_mm2<<<512, 512, 0, stream>>>(yws, ker, (float*)d_out);
}